// Round 20
// baseline (283.156 us; speedup 1.0000x reference)
//
#include <hip/hip_runtime.h>

typedef unsigned short u16;
typedef __bf16 bf16x8 __attribute__((ext_vector_type(8)));
typedef float f32x4 __attribute__((ext_vector_type(4)));
typedef unsigned u32x4 __attribute__((ext_vector_type(4)));

#define B_ 2
#define S_ 2048
#define E_ 1024
#define H_ 16
#define D_ 64
#define M_ (B_ * S_)   // 4096

__device__ inline u16 f2bf(float f) {
  union { float f; unsigned int u; } c; c.f = f;
  unsigned int u = c.u;
  return (u16)((u + 0x7FFFu + ((u >> 16) & 1u)) >> 16);
}

__device__ inline f32x4 mfma16(bf16x8 a, bf16x8 b, f32x4 c) {
  return __builtin_amdgcn_mfma_f32_16x16x32_bf16(a, b, c, 0, 0, 0);
}

__device__ inline void gload16(const void* g, void* lds) {
  __builtin_amdgcn_global_load_lds(
      (const __attribute__((address_space(1))) unsigned int*)g,
      (__attribute__((address_space(3))) unsigned int*)lds, 16, 0, 0);
}

// ---------------- fp32 -> bf16 conversion (weights only) --------------------
struct CvtArgs {
  const float* src[4];
  u16* dst[4];
  int n[4];
};

__global__ __launch_bounds__(256) void cvt_kernel(CvtArgs a) {
  const int arr = blockIdx.y;
  const int n = a.n[arr];
  const float* __restrict__ s = a.src[arr];
  u16* __restrict__ d = a.dst[arr];
  const int stride = gridDim.x * blockDim.x;
  for (int i = blockIdx.x * blockDim.x + threadIdx.x; i * 4 < n; i += stride) {
    const float4 f = *(const float4*)(s + 4 * i);
    ushort4 o;
    o.x = f2bf(f.x); o.y = f2bf(f.y); o.z = f2bf(f.z); o.w = f2bf(f.w);
    *(ushort4*)(d + 4 * i) = o;
  }
}

// ---------------- fused QKV projection: fp32-A convert, 2-deep 5-block ------
// Occupancy experiment: 2-deep ping-pong LDS (32KB) -> 5 blocks/CU = 20
// waves/CU (r18's 3-deep 48KB capped at 3 blocks/CU = 12 waves; counters
// showed everything <30% utilized = latency-bound, occupancy is the lever).
// T3 minimum 2-phase recipe (m248): issue stage(t+1) [writeA + loadB] and
// loadA(t+2) BEFORE compute(t); one vmcnt(0)+lgkmcnt(0)+barrier per iter.
// Single static A-reg bank: writeA's ds_writes consume regs at issue (in
// order) before loadA's WAR reuse -- no runtime bank indexing (rule #20).
__global__ __launch_bounds__(256, 5) void qkv_gemm(
    const float* __restrict__ qf, const float* __restrict__ kf,
    const float* __restrict__ vf, const u16* __restrict__ Wqb,
    const u16* __restrict__ Wkb, const u16* __restrict__ Wvb,
    u16* __restrict__ Qh, u16* __restrict__ Kh, u16* __restrict__ Vt) {
  constexpr int BM = 128, BN = 128, BK = 32;
  __shared__ alignas(16) u16 As[2][BM * BK];
  __shared__ alignas(16) u16 Bs[2][BN * BK];

  const int wg = blockIdx.x;           // 0..767, xcd-bucketed
  const int xcd = wg & 7, idx = wg >> 3;
  const int nb = idx & 7, mz = idx >> 3;
  const int z = mz >> 2;
  const int m0 = (xcd * 4 + (mz & 3)) * BM, n0 = nb * BN;

  const float* A = (z == 0) ? qf  : (z == 1) ? kf  : vf;
  const u16* Bt  = (z == 0) ? Wqb : (z == 1) ? Wkb : Wvb;
  u16* outp      = (z == 0) ? Qh  : (z == 1) ? Kh  : Vt;

  const int tid = threadIdx.x;
  const int wave = tid >> 6, lane = tid & 63;
  const int wm = (wave >> 1) * 64, wn = (wave & 1) * 64;
  const int fr = lane & 15, fc = lane >> 4;
  const int lrow = lane >> 2;
  const int lcol_sw = (((lane & 3) ^ ((lrow >> 1) & 3)) * 8);  // B src swizzle

  const int arow_sub = lane >> 3;          // 0..7
  const int acol = (lane & 7) * 4;         // float col
  const int a_chunkbase = wave * 2;

  f32x4 acc[4][4] = {};

  u16 *aA = As[0], *aB = As[1];
  u16 *bA = Bs[0], *bB = Bs[1];

  float4 areg[4];   // single A bank (next tile's fp32 data)

  auto loadA = [&](int k0) {
#pragma unroll
    for (int ci = 0; ci < 2; ++ci)
#pragma unroll
      for (int i2 = 0; i2 < 2; ++i2) {
        const int row = (a_chunkbase + ci) * 16 + i2 * 8 + arow_sub;
        areg[ci * 2 + i2] = *(const float4*)(A + (size_t)(m0 + row) * E_ + k0 + acol);
      }
  };
  auto writeA = [&](u16* as) {
#pragma unroll
    for (int ci = 0; ci < 2; ++ci)
#pragma unroll
      for (int i2 = 0; i2 < 2; ++i2) {
        const int rowLoc = i2 * 8 + arow_sub;
        const int row = (a_chunkbase + ci) * 16 + rowLoc;
        const float4 f = areg[ci * 2 + i2];
        unsigned d0, d1;
        asm("v_cvt_pk_bf16_f32 %0, %1, %2" : "=v"(d0) : "v"(f.x), "v"(f.y));
        asm("v_cvt_pk_bf16_f32 %0, %1, %2" : "=v"(d1) : "v"(f.z), "v"(f.w));
        const int slot = (acol >> 3) ^ ((rowLoc >> 1) & 3);
        const int half = (acol >> 2) & 1;
        *(uint2*)(&as[row * 32 + slot * 8 + half * 4]) = make_uint2(d0, d1);
      }
  };
  auto loadB = [&](int k0, u16* bs) {
#pragma unroll
    for (int i = 0; i < 2; ++i) {
      const int chunk = wave * 2 + i;
      const int row = chunk * 16 + lrow;
      gload16(Bt + (size_t)(n0 + row) * E_ + k0 + lcol_sw, bs + chunk * 16 * BK);
    }
  };

  const int sl = (fc ^ ((fr >> 1) & 3)) * 8;  // swizzled read slot

  auto compute = [&]() {
    bf16x8 af[4], bfr[4];
#pragma unroll
    for (int mi = 0; mi < 4; ++mi)
      af[mi] = *(const bf16x8*)&aA[(wm + mi * 16 + fr) * BK + sl];
#pragma unroll
    for (int ni = 0; ni < 4; ++ni)
      bfr[ni] = *(const bf16x8*)&bA[(wn + ni * 16 + fr) * BK + sl];
    __builtin_amdgcn_s_setprio(1);
#pragma unroll
    for (int mi = 0; mi < 4; ++mi)
#pragma unroll
      for (int ni = 0; ni < 4; ++ni)
        acc[mi][ni] = mfma16(af[mi], bfr[ni], acc[mi][ni]);
    __builtin_amdgcn_s_setprio(0);
    u16* tp;
    tp = aA; aA = aB; aB = tp;
    tp = bA; bA = bB; bB = tp;
  };

  constexpr int NK = E_ / BK;  // 32
  // Prologue: tile0 -> LDS; A(1) regs in flight, drained before loop.
  loadA(0);
  asm volatile("s_waitcnt vmcnt(0)" ::: "memory");
  writeA(aA);
  loadB(0, bA);
  loadA(1 * BK);
  asm volatile("s_waitcnt vmcnt(0) lgkmcnt(0)" ::: "memory");
  __builtin_amdgcn_s_barrier();

  for (int t = 0; t < NK; ++t) {
    // stage next tile first (write-early for A since regs are certified;
    // loads issue-early for max cover under this iter's compute)
    if (t + 1 < NK) {
      writeA(aB);              // A(t+1) regs -> other LDS buf
      loadB((t + 1) * BK, bB); // B(t+1) gload_lds
    }
    if (t + 2 < NK) loadA((t + 2) * BK);  // A(t+2) -> areg (WAR ok: ds_write issued)
    __builtin_amdgcn_sched_barrier(0);

    compute();                 // ds_read + 16 MFMA on current bufs, then swap

    asm volatile("s_waitcnt vmcnt(0) lgkmcnt(0)" ::: "memory");
    __builtin_amdgcn_s_barrier();
  }

#pragma unroll
  for (int mi = 0; mi < 4; ++mi)
#pragma unroll
    for (int ni = 0; ni < 4; ++ni)
#pragma unroll
      for (int r = 0; r < 4; ++r) {
        const int m = m0 + wm + mi * 16 + (fc << 2) + r;
        const int n = n0 + wn + ni * 16 + fr;
        const float v = acc[mi][ni][r];
        const int b = m >> 11, s = m & (S_ - 1), h = n >> 6, d = n & 63;
        if (z != 2) {
          outp[((((size_t)b * H_ + h) * S_ + s) << 6) + d] = f2bf(v);
        } else {
          outp[(((size_t)b * H_ + h) * D_ + d) * S_ + s] = f2bf(v);
        }
      }
}

// ---------------- output projection GEMM (pipelined + swizzled, BM=64) -----
__global__ __launch_bounds__(256, 4) void oproj_gemm(
    const u16* __restrict__ A, const u16* __restrict__ Bt,
    const float* __restrict__ bias, float* __restrict__ outp) {
  constexpr int BM = 64, BN = 128, BK = 32;
  __shared__ alignas(16) u16 As[3][BM * BK];
  __shared__ alignas(16) u16 Bs[3][BN * BK];

  const int wg = blockIdx.x;           // 0..511, xcd-bucketed
  const int xcd = wg & 7, idx = wg >> 3;
  const int nb = idx & 7, mi_ = idx >> 3;
  const int m0 = (xcd * 8 + mi_) * BM, n0 = nb * BN;

  const int tid = threadIdx.x;
  const int wave = tid >> 6, lane = tid & 63;
  const int wm = (wave >> 1) * 32, wn = (wave & 1) * 64;
  const int fr = lane & 15, fc = lane >> 4;
  const int lrow = lane >> 2;
  const int lcol_sw = (((lane & 3) ^ ((lrow >> 1) & 3)) * 8);

  f32x4 acc[2][4] = {};

  u16 *aA = As[0], *aB = As[1], *aC = As[2];
  u16 *bA = Bs[0], *bB = Bs[1], *bC = Bs[2];

  auto stage = [&](int k0, u16* as, u16* bs) {
#pragma unroll
    for (int i = 0; i < 3; ++i) {
      const int c = wave + 4 * i;
      if (c < 4)
        gload16(A + (size_t)(m0 + c * 16 + lrow) * E_ + k0 + lcol_sw, as + c * 16 * BK);
      else
        gload16(Bt + (size_t)(n0 + (c - 4) * 16 + lrow) * E_ + k0 + lcol_sw,
                bs + (c - 4) * 16 * BK);
    }
  };

  constexpr int NK = E_ / BK;  // 32
  stage(0, aA, bA);
  stage(BK, aB, bB);

  const int sl = (fc ^ ((fr >> 1) & 3)) * 8;

  for (int t = 0; t < NK; ++t) {
    if (t + 1 < NK) {
      asm volatile("s_waitcnt vmcnt(3)" ::: "memory");
    } else {
      asm volatile("s_waitcnt vmcnt(0)" ::: "memory");
    }
    __builtin_amdgcn_s_barrier();
    __builtin_amdgcn_sched_barrier(0);

    if (t + 2 < NK) stage((t + 2) * BK, aC, bC);

    bf16x8 af[2], bfr[4];
#pragma unroll
    for (int mi = 0; mi < 2; ++mi)
      af[mi] = *(const bf16x8*)&aA[(wm + mi * 16 + fr) * BK + sl];
#pragma unroll
    for (int ni = 0; ni < 4; ++ni)
      bfr[ni] = *(const bf16x8*)&bA[(wn + ni * 16 + fr) * BK + sl];
    __builtin_amdgcn_s_setprio(1);
#pragma unroll
    for (int mi = 0; mi < 2; ++mi)
#pragma unroll
      for (int ni = 0; ni < 4; ++ni)
        acc[mi][ni] = mfma16(af[mi], bfr[ni], acc[mi][ni]);
    __builtin_amdgcn_s_setprio(0);

    u16* tp;
    tp = aA; aA = aB; aB = aC; aC = tp;
    tp = bA; bA = bB; bB = bC; bC = tp;
  }

#pragma unroll
  for (int mi = 0; mi < 2; ++mi)
#pragma unroll
    for (int ni = 0; ni < 4; ++ni)
#pragma unroll
      for (int r = 0; r < 4; ++r) {
        const int m = m0 + wm + mi * 16 + (fc << 2) + r;
        const int n = n0 + wn + ni * 16 + fr;
        outp[(size_t)m * E_ + n] = acc[mi][ni][r] + bias[n];
      }
}

// ---------------- causal flash attention (KV-tile 128, 2-deep ping-pong) ----
__device__ __forceinline__ void stage_kv128(
    const u16* __restrict__ Kh_head, const u16* __restrict__ Vt_head,
    int kv0, u16* kb, u16* vb, int wq, int lane) {
#pragma unroll
  for (int hh = 0; hh < 2; ++hh)
    gload16(Kh_head + (size_t)(kv0 + hh * 64 + lane) * D_ + wq * 8,
            kb + wq * 1024 + hh * 512);
#pragma unroll
  for (int i = 0; i < 2; ++i) {
    const int c = 2 * wq + i;
    gload16(Vt_head + (size_t)lane * S_ + kv0 + c * 8, vb + c * 512);
  }
}

__global__ __launch_bounds__(512, 4) void flash_attn(
    const u16* __restrict__ Qh, const u16* __restrict__ Kh,
    const u16* __restrict__ Vt, u16* __restrict__ O) {
  __shared__ alignas(16) u16 Kb[2][8192];   // [buf][chunk*1024 + row*8]
  __shared__ alignas(16) u16 Vb[2][8192];   // [buf][chunk*512 + d*8]

  const int i = blockIdx.x;            // 0..511, snake pairing
  const int ch = i >> 8, p = i & 255;
  const int j = (ch << 8) + ((ch & 1) ? (255 - p) : p);
  const int qt = 15 - (j >> 5);
  const int bh = j & 31;

  const int tid = threadIdx.x;
  const int wq = tid >> 6, lane = tid & 63;

  const int q0 = qt * 128;
  const int b = bh >> 4, h = bh & 15;
  constexpr float SC = 0.125f * 1.4426950408889634f;
  const int fr = lane & 15, fc = lane >> 4;

  const u16* Qbase = Qh + ((size_t)bh * S_ + q0 + wq * 16 + fr) * D_ + 8 * fc;
  const bf16x8 qf0 = *(const bf16x8*)Qbase;
  const bf16x8 qf1 = *(const bf16x8*)(Qbase + 32);
  const u16* Kh_head = Kh + (size_t)bh * S_ * D_;
  const u16* Vt_head = Vt + (size_t)bh * D_ * S_;

  float lacc = 0.f;
  f32x4 oacc[4] = {};
  const int nt = qt + 1;   // 128-row kv tiles

  u16 *kA = Kb[0], *kB = Kb[1];
  u16 *vA = Vb[0], *vB = Vb[1];

  stage_kv128(Kh_head, Vt_head, 0, kA, vA, wq, lane);

  for (int t = 0; t < nt; ++t) {
    asm volatile("s_waitcnt vmcnt(0)" ::: "memory");
    __builtin_amdgcn_s_barrier();
    __builtin_amdgcn_sched_barrier(0);

    if (t + 1 < nt)
      stage_kv128(Kh_head, Vt_head, (t + 1) * 128, kB, vB, wq, lane);

    const u16* kb = kA;
    const u16* vb = vA;
    const bool diag = (t == nt - 1);
    const int qg = q0 + wq * 16 + fr;

#pragma unroll
    for (int hh = 0; hh < 2; ++hh) {
      const int kvb = t * 128 + hh * 64;

      f32x4 sacc[4] = {};
      __builtin_amdgcn_s_setprio(1);
#pragma unroll
      for (int ni = 0; ni < 4; ++ni) {
        const bf16x8 k0 = *(const bf16x8*)&kb[fc * 1024 + hh * 512 + (16 * ni + fr) * 8];
        const bf16x8 k1 = *(const bf16x8*)&kb[(fc + 4) * 1024 + hh * 512 + (16 * ni + fr) * 8];
        sacc[ni] = mfma16(k0, qf0, sacc[ni]);
        sacc[ni] = mfma16(k1, qf1, sacc[ni]);
      }
      __builtin_amdgcn_s_setprio(0);

#pragma unroll
      for (int ni = 0; ni < 4; ++ni)
#pragma unroll
        for (int r = 0; r < 4; ++r) {
          const int kvg = kvb + 16 * ni + 4 * fc + r;
          float pv;
          if (diag && kvg > qg) {
            pv = 0.f;
          } else {
            pv = __builtin_amdgcn_exp2f(sacc[ni][r] * SC);
          }
          sacc[ni][r] = pv;
          lacc += pv;
        }

      unsigned w[4][2];
#pragma unroll
      for (int ni = 0; ni < 4; ++ni) {
        asm("v_cvt_pk_bf16_f32 %0, %1, %2"
            : "=v"(w[ni][0]) : "v"(sacc[ni][0]), "v"(sacc[ni][1]));
        asm("v_cvt_pk_bf16_f32 %0, %1, %2"
            : "=v"(w[ni][1]) : "v"(sacc[ni][2]), "v"(sacc[ni][3]));
      }

      unsigned paw0[4], paw1[4];
#pragma unroll
      for (int pair = 0; pair < 2; ++pair) {
        unsigned xx[2], yy[2], tt2[2];
#pragma unroll
        for (int hh2 = 0; hh2 < 2; ++hh2) {
          unsigned a = w[2 * pair][hh2], bb = w[2 * pair + 1][hh2];
          asm volatile("v_permlane32_swap_b32 %0, %1" : "+v"(a), "+v"(bb));
          xx[hh2] = a; yy[hh2] = bb;
          const unsigned s = (fc & 1) ? a : bb;
          tt2[hh2] = (unsigned)__shfl_xor((int)s, 16);
        }
        unsigned* pw_ = pair ? paw1 : paw0;
        pw_[0] = (fc & 1) ? tt2[0] : xx[0];
        pw_[1] = (fc & 1) ? tt2[1] : xx[1];
        pw_[2] = (fc & 1) ? yy[0] : tt2[0];
        pw_[3] = (fc & 1) ? yy[1] : tt2[1];
      }
      bf16x8 pa0, pa1;
      {
        u32x4 t0 = {paw0[0], paw0[1], paw0[2], paw0[3]};
        u32x4 t1 = {paw1[0], paw1[1], paw1[2], paw1[3]};
        __builtin_memcpy(&pa0, &t0, 16);
        __builtin_memcpy(&pa1, &t1, 16);
      }

      __builtin_amdgcn_s_setprio(1);
#pragma unroll
      for (int nd = 0; nd < 4; ++nd) {
        const bf16x8 v0 = *(const bf16x8*)&vb[(hh * 8 + fc) * 512 + (16 * nd + fr) * 8];
        const bf16x8 v1 = *(const bf16x8*)&vb[(hh * 8 + fc + 4) * 512 + (16 * nd + fr) * 8];
        oacc[nd] = mfma16(pa0, v0, oacc[nd]);
        oacc[nd] = mfma16(pa1, v1, oacc[nd]);
      }
      __builtin_amdgcn_s_setprio(0);
    }

    u16* tk = kA; kA = kB; kB = tk;
    u16* tv = vA; vA = vB; vB = tv;
  }

  float l = lacc;
  l += __shfl_xor(l, 16);
  l += __shfl_xor(l, 32);
  float linv[4];
#pragma unroll
  for (int r = 0; r < 4; ++r)
    linv[r] = __builtin_amdgcn_rcpf(__shfl(l, 4 * fc + r));

#pragma unroll
  for (int nd = 0; nd < 4; ++nd) {
#pragma unroll
    for (int r = 0; r < 4; ++r) {
      const int qr = q0 + wq * 16 + (fc << 2) + r;
      const int d = 16 * nd + fr;
      const float v = oacc[nd][r] * linv[r];
      O[((size_t)b * S_ + qr) * E_ + h * D_ + d] = f2bf(v);
    }
  }
}

// ---------------------------------------------------------------------------
extern "C" void kernel_launch(void* const* d_in, const int* in_sizes, int n_in,
                              void* d_out, int out_size, void* d_ws, size_t ws_size,
                              hipStream_t stream) {
  const float* q  = (const float*)d_in[0];
  const float* k  = (const float*)d_in[1];
  const float* v  = (const float*)d_in[2];
  const float* Wq = (const float*)d_in[3];
  const float* Wk = (const float*)d_in[4];
  const float* Wv = (const float*)d_in[5];
  const float* Wo = (const float*)d_in[6];
  const float* bo = (const float*)d_in[7];

  const size_t nBSE = (size_t)M_ * E_;  // 4M elems
  const size_t nEE  = (size_t)E_ * E_;  // 1M elems
  u16* Wqb = (u16*)d_ws;
  u16* Wkb = Wqb + nEE;
  u16* Wvb = Wkb + nEE;
  u16* Wob = Wvb + nEE;
  u16* Qh  = Wob + nEE;
  u16* Kh  = Qh + nBSE;
  u16* Vt  = Kh + nBSE;
  u16* Oa  = Vt + nBSE;

  CvtArgs ca;
  ca.src[0] = Wq; ca.dst[0] = Wqb; ca.n[0] = (int)nEE;
  ca.src[1] = Wk; ca.dst[1] = Wkb; ca.n[1] = (int)nEE;
  ca.src[2] = Wv; ca.dst[2] = Wvb; ca.n[2] = (int)nEE;
  ca.src[3] = Wo; ca.dst[3] = Wob; ca.n[3] = (int)nEE;
  cvt_kernel<<<dim3(256, 4), 256, 0, stream>>>(ca);

  // Fused Q/K/V projections reading fp32 inputs directly: 768 blocks
  qkv_gemm<<<dim3(768), 256, 0, stream>>>(
      q, k, v, Wqb, Wkb, Wvb, Qh, Kh, Vt);
  // 512 blocks x 512 threads: one 128-row q-tile each, snake pairing
  flash_attn<<<dim3(512), 512, 0, stream>>>(Qh, Kh, Vt, Oa);
  // O-projection: 512 blocks, xcd-bucketed, pipelined
  oproj_gemm<<<dim3(512), 256, 0, stream>>>(Oa, Wob, bo, (float*)d_out);
}

// Round 21
// 206.477 us; speedup vs baseline: 1.3714x; 1.3714x over previous
//
#include <hip/hip_runtime.h>

typedef unsigned short u16;
typedef __bf16 bf16x8 __attribute__((ext_vector_type(8)));
typedef float f32x4 __attribute__((ext_vector_type(4)));
typedef unsigned u32x4 __attribute__((ext_vector_type(4)));

#define B_ 2
#define S_ 2048
#define E_ 1024
#define H_ 16
#define D_ 64
#define M_ (B_ * S_)   // 4096

__device__ inline u16 f2bf(float f) {
  union { float f; unsigned int u; } c; c.f = f;
  unsigned int u = c.u;
  return (u16)((u + 0x7FFFu + ((u >> 16) & 1u)) >> 16);
}

__device__ inline f32x4 mfma16(bf16x8 a, bf16x8 b, f32x4 c) {
  return __builtin_amdgcn_mfma_f32_16x16x32_bf16(a, b, c, 0, 0, 0);
}

__device__ inline void gload16(const void* g, void* lds) {
  __builtin_amdgcn_global_load_lds(
      (const __attribute__((address_space(1))) unsigned int*)g,
      (__attribute__((address_space(3))) unsigned int*)lds, 16, 0, 0);
}

// ---------------- fp32 -> bf16 conversion (weights only) --------------------
struct CvtArgs {
  const float* src[4];
  u16* dst[4];
  int n[4];
};

__global__ __launch_bounds__(256) void cvt_kernel(CvtArgs a) {
  const int arr = blockIdx.y;
  const int n = a.n[arr];
  const float* __restrict__ s = a.src[arr];
  u16* __restrict__ d = a.dst[arr];
  const int stride = gridDim.x * blockDim.x;
  for (int i = blockIdx.x * blockDim.x + threadIdx.x; i * 4 < n; i += stride) {
    const float4 f = *(const float4*)(s + 4 * i);
    ushort4 o;
    o.x = f2bf(f.x); o.y = f2bf(f.y); o.z = f2bf(f.z); o.w = f2bf(f.w);
    *(ushort4*)(d + 4 * i) = o;
  }
}

// ---------------- fused QKV projection: r18 pipe, A ping-pong, 4 blocks/CU --
// r18's 3-deep counted-vmcnt schedule unchanged, but A's LDS is PING-PONG
// (r18's rotation only ever wrote aB / read aA -- the third A buffer idled).
// LDS 48KB -> 40KB => 4 blocks/CU = 16 waves/CU (was 12). launch_bounds
// (256,4): VGPR cap 128 >= r18's 84 usage -> no spill (r20's (256,5) cap 102
// < ~116 live set spilled catastrophically).
__global__ __launch_bounds__(256, 4) void qkv_gemm(
    const float* __restrict__ qf, const float* __restrict__ kf,
    const float* __restrict__ vf, const u16* __restrict__ Wqb,
    const u16* __restrict__ Wkb, const u16* __restrict__ Wvb,
    u16* __restrict__ Qh, u16* __restrict__ Kh, u16* __restrict__ Vt) {
  constexpr int BM = 128, BN = 128, BK = 32;
  __shared__ alignas(16) u16 As[2][BM * BK];   // 16KB (ping-pong)
  __shared__ alignas(16) u16 Bs[3][BN * BK];   // 24KB (3-deep)

  const int wg = blockIdx.x;           // 0..767, xcd-bucketed
  const int xcd = wg & 7, idx = wg >> 3;
  const int nb = idx & 7, mz = idx >> 3;
  const int z = mz >> 2;
  const int m0 = (xcd * 4 + (mz & 3)) * BM, n0 = nb * BN;

  const float* A = (z == 0) ? qf  : (z == 1) ? kf  : vf;
  const u16* Bt  = (z == 0) ? Wqb : (z == 1) ? Wkb : Wvb;
  u16* outp      = (z == 0) ? Qh  : (z == 1) ? Kh  : Vt;

  const int tid = threadIdx.x;
  const int wave = tid >> 6, lane = tid & 63;
  const int wm = (wave >> 1) * 64, wn = (wave & 1) * 64;
  const int fr = lane & 15, fc = lane >> 4;
  const int lrow = lane >> 2;
  const int lcol_sw = (((lane & 3) ^ ((lrow >> 1) & 3)) * 8);  // B src swizzle

  const int arow_sub = lane >> 3;          // 0..7
  const int acol = (lane & 7) * 4;         // float col
  const int a_chunkbase = wave * 2;

  f32x4 acc[4][4] = {};

  u16 *aA = As[0], *aB = As[1];
  u16 *bA = Bs[0], *bB = Bs[1], *bC = Bs[2];

  float4 areg0[4], areg1[4];   // dual A banks; every access statically named

  auto loadA0 = [&](int k0) {
#pragma unroll
    for (int ci = 0; ci < 2; ++ci)
#pragma unroll
      for (int i2 = 0; i2 < 2; ++i2) {
        const int row = (a_chunkbase + ci) * 16 + i2 * 8 + arow_sub;
        areg0[ci * 2 + i2] = *(const float4*)(A + (size_t)(m0 + row) * E_ + k0 + acol);
      }
  };
  auto loadA1 = [&](int k0) {
#pragma unroll
    for (int ci = 0; ci < 2; ++ci)
#pragma unroll
      for (int i2 = 0; i2 < 2; ++i2) {
        const int row = (a_chunkbase + ci) * 16 + i2 * 8 + arow_sub;
        areg1[ci * 2 + i2] = *(const float4*)(A + (size_t)(m0 + row) * E_ + k0 + acol);
      }
  };
  auto writeA0 = [&](u16* as) {
#pragma unroll
    for (int ci = 0; ci < 2; ++ci)
#pragma unroll
      for (int i2 = 0; i2 < 2; ++i2) {
        const int rowLoc = i2 * 8 + arow_sub;
        const int row = (a_chunkbase + ci) * 16 + rowLoc;
        const float4 f = areg0[ci * 2 + i2];
        unsigned d0, d1;
        asm("v_cvt_pk_bf16_f32 %0, %1, %2" : "=v"(d0) : "v"(f.x), "v"(f.y));
        asm("v_cvt_pk_bf16_f32 %0, %1, %2" : "=v"(d1) : "v"(f.z), "v"(f.w));
        const int slot = (acol >> 3) ^ ((rowLoc >> 1) & 3);
        const int half = (acol >> 2) & 1;
        *(uint2*)(&as[row * 32 + slot * 8 + half * 4]) = make_uint2(d0, d1);
      }
  };
  auto writeA1 = [&](u16* as) {
#pragma unroll
    for (int ci = 0; ci < 2; ++ci)
#pragma unroll
      for (int i2 = 0; i2 < 2; ++i2) {
        const int rowLoc = i2 * 8 + arow_sub;
        const int row = (a_chunkbase + ci) * 16 + rowLoc;
        const float4 f = areg1[ci * 2 + i2];
        unsigned d0, d1;
        asm("v_cvt_pk_bf16_f32 %0, %1, %2" : "=v"(d0) : "v"(f.x), "v"(f.y));
        asm("v_cvt_pk_bf16_f32 %0, %1, %2" : "=v"(d1) : "v"(f.z), "v"(f.w));
        const int slot = (acol >> 3) ^ ((rowLoc >> 1) & 3);
        const int half = (acol >> 2) & 1;
        *(uint2*)(&as[row * 32 + slot * 8 + half * 4]) = make_uint2(d0, d1);
      }
  };
  auto loadB = [&](int k0, u16* bs) {
#pragma unroll
    for (int i = 0; i < 2; ++i) {
      const int chunk = wave * 2 + i;
      const int row = chunk * 16 + lrow;
      gload16(Bt + (size_t)(n0 + row) * E_ + k0 + lcol_sw, bs + chunk * 16 * BK);
    }
  };

  const int sl = (fc ^ ((fr >> 1) & 3)) * 8;  // swizzled read slot

  auto compute = [&]() {
    bf16x8 af[4], bfr[4];
#pragma unroll
    for (int mi = 0; mi < 4; ++mi)
      af[mi] = *(const bf16x8*)&aA[(wm + mi * 16 + fr) * BK + sl];
#pragma unroll
    for (int ni = 0; ni < 4; ++ni)
      bfr[ni] = *(const bf16x8*)&bA[(wn + ni * 16 + fr) * BK + sl];
    __builtin_amdgcn_s_setprio(1);
#pragma unroll
    for (int mi = 0; mi < 4; ++mi)
#pragma unroll
      for (int ni = 0; ni < 4; ++ni)
        acc[mi][ni] = mfma16(af[mi], bfr[ni], acc[mi][ni]);
    __builtin_amdgcn_s_setprio(0);
    u16* tp;
    tp = aA; aA = aB; aB = tp;            // A ping-pong
    tp = bA; bA = bB; bB = bC; bC = tp;   // B 3-deep rotation
  };

  constexpr int NK = E_ / BK;  // 32 (even)
  // Prologue: A(0) via bank0 -> aA; then A(1)->bank1, B(0); A(2)->bank0, B(1).
  loadA0(0);
  asm volatile("s_waitcnt vmcnt(0)" ::: "memory");
  writeA0(aA);
  loadA1(1 * BK);  loadB(0, bA);
  loadA0(2 * BK);  loadB(1 * BK, bB);
  // queue (oldest first): A(1)x4, B(0)x2, A(2)x4, B(1)x2 = 12

  for (int tt = 0; tt < NK; tt += 2) {
    {  // even sub-iter t = tt: bank1 holds A(t+1); write-late post-barrier
      const int t = tt;
      if (t + 3 < NK) {
        asm volatile("s_waitcnt vmcnt(6)" ::: "memory");  // A(t+1) regs + B(t) LDS
      } else {
        asm volatile("s_waitcnt vmcnt(0)" ::: "memory");
      }
      asm volatile("s_waitcnt lgkmcnt(0)" ::: "memory");  // drain prev A-writes
      __builtin_amdgcn_s_barrier();
      __builtin_amdgcn_sched_barrier(0);
      writeA1(aB);                       // A(t+1) -> buffer read next iter
      if (t + 3 < NK) loadA1((t + 3) * BK);
      if (t + 2 < NK) loadB((t + 2) * BK, bC);
      __builtin_amdgcn_sched_barrier(0);
      compute();
    }
    {  // odd sub-iter t = tt+1: bank0 holds A(t+1)
      const int t = tt + 1;
      if (t + 1 < NK) {
        if (t + 3 < NK) {
          asm volatile("s_waitcnt vmcnt(6)" ::: "memory");
        } else {
          asm volatile("s_waitcnt vmcnt(0)" ::: "memory");
        }
      } else {
        asm volatile("s_waitcnt vmcnt(0)" ::: "memory");
      }
      asm volatile("s_waitcnt lgkmcnt(0)" ::: "memory");
      __builtin_amdgcn_s_barrier();
      __builtin_amdgcn_sched_barrier(0);
      if (t + 1 < NK) writeA0(aB);
      if (t + 3 < NK) loadA0((t + 3) * BK);
      if (t + 2 < NK) loadB((t + 2) * BK, bC);
      __builtin_amdgcn_sched_barrier(0);
      compute();
    }
  }

#pragma unroll
  for (int mi = 0; mi < 4; ++mi)
#pragma unroll
    for (int ni = 0; ni < 4; ++ni)
#pragma unroll
      for (int r = 0; r < 4; ++r) {
        const int m = m0 + wm + mi * 16 + (fc << 2) + r;
        const int n = n0 + wn + ni * 16 + fr;
        const float v = acc[mi][ni][r];
        const int b = m >> 11, s = m & (S_ - 1), h = n >> 6, d = n & 63;
        if (z != 2) {
          outp[((((size_t)b * H_ + h) * S_ + s) << 6) + d] = f2bf(v);
        } else {
          outp[(((size_t)b * H_ + h) * D_ + d) * S_ + s] = f2bf(v);
        }
      }
}

// ---------------- output projection GEMM (pipelined + swizzled, BM=64) -----
__global__ __launch_bounds__(256, 4) void oproj_gemm(
    const u16* __restrict__ A, const u16* __restrict__ Bt,
    const float* __restrict__ bias, float* __restrict__ outp) {
  constexpr int BM = 64, BN = 128, BK = 32;
  __shared__ alignas(16) u16 As[3][BM * BK];
  __shared__ alignas(16) u16 Bs[3][BN * BK];

  const int wg = blockIdx.x;           // 0..511, xcd-bucketed
  const int xcd = wg & 7, idx = wg >> 3;
  const int nb = idx & 7, mi_ = idx >> 3;
  const int m0 = (xcd * 8 + mi_) * BM, n0 = nb * BN;

  const int tid = threadIdx.x;
  const int wave = tid >> 6, lane = tid & 63;
  const int wm = (wave >> 1) * 32, wn = (wave & 1) * 64;
  const int fr = lane & 15, fc = lane >> 4;
  const int lrow = lane >> 2;
  const int lcol_sw = (((lane & 3) ^ ((lrow >> 1) & 3)) * 8);

  f32x4 acc[2][4] = {};

  u16 *aA = As[0], *aB = As[1], *aC = As[2];
  u16 *bA = Bs[0], *bB = Bs[1], *bC = Bs[2];

  auto stage = [&](int k0, u16* as, u16* bs) {
#pragma unroll
    for (int i = 0; i < 3; ++i) {
      const int c = wave + 4 * i;
      if (c < 4)
        gload16(A + (size_t)(m0 + c * 16 + lrow) * E_ + k0 + lcol_sw, as + c * 16 * BK);
      else
        gload16(Bt + (size_t)(n0 + (c - 4) * 16 + lrow) * E_ + k0 + lcol_sw,
                bs + (c - 4) * 16 * BK);
    }
  };

  constexpr int NK = E_ / BK;  // 32
  stage(0, aA, bA);
  stage(BK, aB, bB);

  const int sl = (fc ^ ((fr >> 1) & 3)) * 8;

  for (int t = 0; t < NK; ++t) {
    if (t + 1 < NK) {
      asm volatile("s_waitcnt vmcnt(3)" ::: "memory");
    } else {
      asm volatile("s_waitcnt vmcnt(0)" ::: "memory");
    }
    __builtin_amdgcn_s_barrier();
    __builtin_amdgcn_sched_barrier(0);

    if (t + 2 < NK) stage((t + 2) * BK, aC, bC);

    bf16x8 af[2], bfr[4];
#pragma unroll
    for (int mi = 0; mi < 2; ++mi)
      af[mi] = *(const bf16x8*)&aA[(wm + mi * 16 + fr) * BK + sl];
#pragma unroll
    for (int ni = 0; ni < 4; ++ni)
      bfr[ni] = *(const bf16x8*)&bA[(wn + ni * 16 + fr) * BK + sl];
    __builtin_amdgcn_s_setprio(1);
#pragma unroll
    for (int mi = 0; mi < 2; ++mi)
#pragma unroll
      for (int ni = 0; ni < 4; ++ni)
        acc[mi][ni] = mfma16(af[mi], bfr[ni], acc[mi][ni]);
    __builtin_amdgcn_s_setprio(0);

    u16* tp;
    tp = aA; aA = aB; aB = aC; aC = tp;
    tp = bA; bA = bB; bB = bC; bC = tp;
  }

#pragma unroll
  for (int mi = 0; mi < 2; ++mi)
#pragma unroll
    for (int ni = 0; ni < 4; ++ni)
#pragma unroll
      for (int r = 0; r < 4; ++r) {
        const int m = m0 + wm + mi * 16 + (fc << 2) + r;
        const int n = n0 + wn + ni * 16 + fr;
        outp[(size_t)m * E_ + n] = acc[mi][ni][r] + bias[n];
      }
}

// ---------------- causal flash attention (KV-tile 128, 2-deep ping-pong) ----
__device__ __forceinline__ void stage_kv128(
    const u16* __restrict__ Kh_head, const u16* __restrict__ Vt_head,
    int kv0, u16* kb, u16* vb, int wq, int lane) {
#pragma unroll
  for (int hh = 0; hh < 2; ++hh)
    gload16(Kh_head + (size_t)(kv0 + hh * 64 + lane) * D_ + wq * 8,
            kb + wq * 1024 + hh * 512);
#pragma unroll
  for (int i = 0; i < 2; ++i) {
    const int c = 2 * wq + i;
    gload16(Vt_head + (size_t)lane * S_ + kv0 + c * 8, vb + c * 512);
  }
}

__global__ __launch_bounds__(512, 4) void flash_attn(
    const u16* __restrict__ Qh, const u16* __restrict__ Kh,
    const u16* __restrict__ Vt, u16* __restrict__ O) {
  __shared__ alignas(16) u16 Kb[2][8192];   // [buf][chunk*1024 + row*8]
  __shared__ alignas(16) u16 Vb[2][8192];   // [buf][chunk*512 + d*8]

  const int i = blockIdx.x;            // 0..511, snake pairing
  const int ch = i >> 8, p = i & 255;
  const int j = (ch << 8) + ((ch & 1) ? (255 - p) : p);
  const int qt = 15 - (j >> 5);
  const int bh = j & 31;

  const int tid = threadIdx.x;
  const int wq = tid >> 6, lane = tid & 63;

  const int q0 = qt * 128;
  const int b = bh >> 4, h = bh & 15;
  constexpr float SC = 0.125f * 1.4426950408889634f;
  const int fr = lane & 15, fc = lane >> 4;

  const u16* Qbase = Qh + ((size_t)bh * S_ + q0 + wq * 16 + fr) * D_ + 8 * fc;
  const bf16x8 qf0 = *(const bf16x8*)Qbase;
  const bf16x8 qf1 = *(const bf16x8*)(Qbase + 32);
  const u16* Kh_head = Kh + (size_t)bh * S_ * D_;
  const u16* Vt_head = Vt + (size_t)bh * D_ * S_;

  float lacc = 0.f;
  f32x4 oacc[4] = {};
  const int nt = qt + 1;   // 128-row kv tiles

  u16 *kA = Kb[0], *kB = Kb[1];
  u16 *vA = Vb[0], *vB = Vb[1];

  stage_kv128(Kh_head, Vt_head, 0, kA, vA, wq, lane);

  for (int t = 0; t < nt; ++t) {
    asm volatile("s_waitcnt vmcnt(0)" ::: "memory");
    __builtin_amdgcn_s_barrier();
    __builtin_amdgcn_sched_barrier(0);

    if (t + 1 < nt)
      stage_kv128(Kh_head, Vt_head, (t + 1) * 128, kB, vB, wq, lane);

    const u16* kb = kA;
    const u16* vb = vA;
    const bool diag = (t == nt - 1);
    const int qg = q0 + wq * 16 + fr;

#pragma unroll
    for (int hh = 0; hh < 2; ++hh) {
      const int kvb = t * 128 + hh * 64;

      f32x4 sacc[4] = {};
      __builtin_amdgcn_s_setprio(1);
#pragma unroll
      for (int ni = 0; ni < 4; ++ni) {
        const bf16x8 k0 = *(const bf16x8*)&kb[fc * 1024 + hh * 512 + (16 * ni + fr) * 8];
        const bf16x8 k1 = *(const bf16x8*)&kb[(fc + 4) * 1024 + hh * 512 + (16 * ni + fr) * 8];
        sacc[ni] = mfma16(k0, qf0, sacc[ni]);
        sacc[ni] = mfma16(k1, qf1, sacc[ni]);
      }
      __builtin_amdgcn_s_setprio(0);

#pragma unroll
      for (int ni = 0; ni < 4; ++ni)
#pragma unroll
        for (int r = 0; r < 4; ++r) {
          const int kvg = kvb + 16 * ni + 4 * fc + r;
          float pv;
          if (diag && kvg > qg) {
            pv = 0.f;
          } else {
            pv = __builtin_amdgcn_exp2f(sacc[ni][r] * SC);
          }
          sacc[ni][r] = pv;
          lacc += pv;
        }

      unsigned w[4][2];
#pragma unroll
      for (int ni = 0; ni < 4; ++ni) {
        asm("v_cvt_pk_bf16_f32 %0, %1, %2"
            : "=v"(w[ni][0]) : "v"(sacc[ni][0]), "v"(sacc[ni][1]));
        asm("v_cvt_pk_bf16_f32 %0, %1, %2"
            : "=v"(w[ni][1]) : "v"(sacc[ni][2]), "v"(sacc[ni][3]));
      }

      unsigned paw0[4], paw1[4];
#pragma unroll
      for (int pair = 0; pair < 2; ++pair) {
        unsigned xx[2], yy[2], tt2[2];
#pragma unroll
        for (int hh2 = 0; hh2 < 2; ++hh2) {
          unsigned a = w[2 * pair][hh2], bb = w[2 * pair + 1][hh2];
          asm volatile("v_permlane32_swap_b32 %0, %1" : "+v"(a), "+v"(bb));
          xx[hh2] = a; yy[hh2] = bb;
          const unsigned s = (fc & 1) ? a : bb;
          tt2[hh2] = (unsigned)__shfl_xor((int)s, 16);
        }
        unsigned* pw_ = pair ? paw1 : paw0;
        pw_[0] = (fc & 1) ? tt2[0] : xx[0];
        pw_[1] = (fc & 1) ? tt2[1] : xx[1];
        pw_[2] = (fc & 1) ? yy[0] : tt2[0];
        pw_[3] = (fc & 1) ? yy[1] : tt2[1];
      }
      bf16x8 pa0, pa1;
      {
        u32x4 t0 = {paw0[0], paw0[1], paw0[2], paw0[3]};
        u32x4 t1 = {paw1[0], paw1[1], paw1[2], paw1[3]};
        __builtin_memcpy(&pa0, &t0, 16);
        __builtin_memcpy(&pa1, &t1, 16);
      }

      __builtin_amdgcn_s_setprio(1);
#pragma unroll
      for (int nd = 0; nd < 4; ++nd) {
        const bf16x8 v0 = *(const bf16x8*)&vb[(hh * 8 + fc) * 512 + (16 * nd + fr) * 8];
        const bf16x8 v1 = *(const bf16x8*)&vb[(hh * 8 + fc + 4) * 512 + (16 * nd + fr) * 8];
        oacc[nd] = mfma16(pa0, v0, oacc[nd]);
        oacc[nd] = mfma16(pa1, v1, oacc[nd]);
      }
      __builtin_amdgcn_s_setprio(0);
    }

    u16* tk = kA; kA = kB; kB = tk;
    u16* tv = vA; vA = vB; vB = tv;
  }

  float l = lacc;
  l += __shfl_xor(l, 16);
  l += __shfl_xor(l, 32);
  float linv[4];
#pragma unroll
  for (int r = 0; r < 4; ++r)
    linv[r] = __builtin_amdgcn_rcpf(__shfl(l, 4 * fc + r));

#pragma unroll
  for (int nd = 0; nd < 4; ++nd) {
#pragma unroll
    for (int r = 0; r < 4; ++r) {
      const int qr = q0 + wq * 16 + (fc << 2) + r;
      const int d = 16 * nd + fr;
      const float v = oacc[nd][r] * linv[r];
      O[((size_t)b * S_ + qr) * E_ + h * D_ + d] = f2bf(v);
    }
  }
}

// ---------------------------------------------------------------------------
extern "C" void kernel_launch(void* const* d_in, const int* in_sizes, int n_in,
                              void* d_out, int out_size, void* d_ws, size_t ws_size,
                              hipStream_t stream) {
  const float* q  = (const float*)d_in[0];
  const float* k  = (const float*)d_in[1];
  const float* v  = (const float*)d_in[2];
  const float* Wq = (const float*)d_in[3];
  const float* Wk = (const float*)d_in[4];
  const float* Wv = (const float*)d_in[5];
  const float* Wo = (const float*)d_in[6];
  const float* bo = (const float*)d_in[7];

  const size_t nBSE = (size_t)M_ * E_;  // 4M elems
  const size_t nEE  = (size_t)E_ * E_;  // 1M elems
  u16* Wqb = (u16*)d_ws;
  u16* Wkb = Wqb + nEE;
  u16* Wvb = Wkb + nEE;
  u16* Wob = Wvb + nEE;
  u16* Qh  = Wob + nEE;
  u16* Kh  = Qh + nBSE;
  u16* Vt  = Kh + nBSE;
  u16* Oa  = Vt + nBSE;

  CvtArgs ca;
  ca.src[0] = Wq; ca.dst[0] = Wqb; ca.n[0] = (int)nEE;
  ca.src[1] = Wk; ca.dst[1] = Wkb; ca.n[1] = (int)nEE;
  ca.src[2] = Wv; ca.dst[2] = Wvb; ca.n[2] = (int)nEE;
  ca.src[3] = Wo; ca.dst[3] = Wob; ca.n[3] = (int)nEE;
  cvt_kernel<<<dim3(256, 4), 256, 0, stream>>>(ca);

  // Fused Q/K/V projections reading fp32 inputs directly: 768 blocks
  qkv_gemm<<<dim3(768), 256, 0, stream>>>(
      q, k, v, Wqb, Wkb, Wvb, Qh, Kh, Vt);
  // 512 blocks x 512 threads: one 128-row q-tile each, snake pairing
  flash_attn<<<dim3(512), 512, 0, stream>>>(Qh, Kh, Vt, Oa);
  // O-projection: 512 blocks, xcd-bucketed, pipelined
  oproj_gemm<<<dim3(512), 256, 0, stream>>>(Oa, Wob, bo, (float*)d_out);
}

// Round 22
// 102.662 us; speedup vs baseline: 2.7581x; 2.0112x over previous
//
#include <hip/hip_runtime.h>

typedef unsigned short u16;
typedef __bf16 bf16x8 __attribute__((ext_vector_type(8)));
typedef float f32x4 __attribute__((ext_vector_type(4)));
typedef unsigned u32x4 __attribute__((ext_vector_type(4)));

#define B_ 2
#define S_ 2048
#define E_ 1024
#define H_ 16
#define D_ 64
#define M_ (B_ * S_)   // 4096

__device__ inline u16 f2bf(float f) {
  union { float f; unsigned int u; } c; c.f = f;
  unsigned int u = c.u;
  return (u16)((u + 0x7FFFu + ((u >> 16) & 1u)) >> 16);
}

__device__ inline f32x4 mfma16(bf16x8 a, bf16x8 b, f32x4 c) {
  return __builtin_amdgcn_mfma_f32_16x16x32_bf16(a, b, c, 0, 0, 0);
}

__device__ inline void gload16(const void* g, void* lds) {
  __builtin_amdgcn_global_load_lds(
      (const __attribute__((address_space(1))) unsigned int*)g,
      (__attribute__((address_space(3))) unsigned int*)lds, 16, 0, 0);
}

// ---------------- fp32 -> bf16 conversion (weights only) --------------------
struct CvtArgs {
  const float* src[4];
  u16* dst[4];
  int n[4];
};

__global__ __launch_bounds__(256) void cvt_kernel(CvtArgs a) {
  const int arr = blockIdx.y;
  const int n = a.n[arr];
  const float* __restrict__ s = a.src[arr];
  u16* __restrict__ d = a.dst[arr];
  const int stride = gridDim.x * blockDim.x;
  for (int i = blockIdx.x * blockDim.x + threadIdx.x; i * 4 < n; i += stride) {
    const float4 f = *(const float4*)(s + 4 * i);
    ushort4 o;
    o.x = f2bf(f.x); o.y = f2bf(f.y); o.z = f2bf(f.z); o.w = f2bf(f.w);
    *(ushort4*)(d + 4 * i) = o;
  }
}

// ---------------- fused QKV projection: fp32-A convert, write-late pipe -----
// PROVEN r18/r19 config (103.1us total). 3-deep B, 3-slot A rotation,
// launch_bounds(256,3): 84 arch VGPR + 64 acc = 148 fits the 3-wave/SIMD cap
// (~170). (256,4)/(256,5) variants spill (r20/r21): acc counts against the
// unified budget, so 4-wave cap 128 < 148. Occupancy is register-capped at
// 3 blocks/CU for this tile shape -- do not raise launch_bounds.
__global__ __launch_bounds__(256, 3) void qkv_gemm(
    const float* __restrict__ qf, const float* __restrict__ kf,
    const float* __restrict__ vf, const u16* __restrict__ Wqb,
    const u16* __restrict__ Wkb, const u16* __restrict__ Wvb,
    u16* __restrict__ Qh, u16* __restrict__ Kh, u16* __restrict__ Vt) {
  constexpr int BM = 128, BN = 128, BK = 32;
  __shared__ alignas(16) u16 As[3][BM * BK];
  __shared__ alignas(16) u16 Bs[3][BN * BK];

  const int wg = blockIdx.x;           // 0..767, xcd-bucketed
  const int xcd = wg & 7, idx = wg >> 3;
  const int nb = idx & 7, mz = idx >> 3;
  const int z = mz >> 2;
  const int m0 = (xcd * 4 + (mz & 3)) * BM, n0 = nb * BN;

  const float* A = (z == 0) ? qf  : (z == 1) ? kf  : vf;
  const u16* Bt  = (z == 0) ? Wqb : (z == 1) ? Wkb : Wvb;
  u16* outp      = (z == 0) ? Qh  : (z == 1) ? Kh  : Vt;

  const int tid = threadIdx.x;
  const int wave = tid >> 6, lane = tid & 63;
  const int wm = (wave >> 1) * 64, wn = (wave & 1) * 64;
  const int fr = lane & 15, fc = lane >> 4;
  const int lrow = lane >> 2;
  const int lcol_sw = (((lane & 3) ^ ((lrow >> 1) & 3)) * 8);  // B src swizzle

  const int arow_sub = lane >> 3;          // 0..7
  const int acol = (lane & 7) * 4;         // float col
  const int a_chunkbase = wave * 2;

  f32x4 acc[4][4] = {};

  u16 *aA = As[0], *aB = As[1], *aC = As[2];
  u16 *bA = Bs[0], *bB = Bs[1], *bC = Bs[2];

  float4 areg0[4], areg1[4];   // dual A banks; every access statically named

  auto loadA0 = [&](int k0) {
#pragma unroll
    for (int ci = 0; ci < 2; ++ci)
#pragma unroll
      for (int i2 = 0; i2 < 2; ++i2) {
        const int row = (a_chunkbase + ci) * 16 + i2 * 8 + arow_sub;
        areg0[ci * 2 + i2] = *(const float4*)(A + (size_t)(m0 + row) * E_ + k0 + acol);
      }
  };
  auto loadA1 = [&](int k0) {
#pragma unroll
    for (int ci = 0; ci < 2; ++ci)
#pragma unroll
      for (int i2 = 0; i2 < 2; ++i2) {
        const int row = (a_chunkbase + ci) * 16 + i2 * 8 + arow_sub;
        areg1[ci * 2 + i2] = *(const float4*)(A + (size_t)(m0 + row) * E_ + k0 + acol);
      }
  };
  auto writeA0 = [&](u16* as) {
#pragma unroll
    for (int ci = 0; ci < 2; ++ci)
#pragma unroll
      for (int i2 = 0; i2 < 2; ++i2) {
        const int rowLoc = i2 * 8 + arow_sub;
        const int row = (a_chunkbase + ci) * 16 + rowLoc;
        const float4 f = areg0[ci * 2 + i2];
        unsigned d0, d1;
        asm("v_cvt_pk_bf16_f32 %0, %1, %2" : "=v"(d0) : "v"(f.x), "v"(f.y));
        asm("v_cvt_pk_bf16_f32 %0, %1, %2" : "=v"(d1) : "v"(f.z), "v"(f.w));
        const int slot = (acol >> 3) ^ ((rowLoc >> 1) & 3);
        const int half = (acol >> 2) & 1;
        *(uint2*)(&as[row * 32 + slot * 8 + half * 4]) = make_uint2(d0, d1);
      }
  };
  auto writeA1 = [&](u16* as) {
#pragma unroll
    for (int ci = 0; ci < 2; ++ci)
#pragma unroll
      for (int i2 = 0; i2 < 2; ++i2) {
        const int rowLoc = i2 * 8 + arow_sub;
        const int row = (a_chunkbase + ci) * 16 + rowLoc;
        const float4 f = areg1[ci * 2 + i2];
        unsigned d0, d1;
        asm("v_cvt_pk_bf16_f32 %0, %1, %2" : "=v"(d0) : "v"(f.x), "v"(f.y));
        asm("v_cvt_pk_bf16_f32 %0, %1, %2" : "=v"(d1) : "v"(f.z), "v"(f.w));
        const int slot = (acol >> 3) ^ ((rowLoc >> 1) & 3);
        const int half = (acol >> 2) & 1;
        *(uint2*)(&as[row * 32 + slot * 8 + half * 4]) = make_uint2(d0, d1);
      }
  };
  auto loadB = [&](int k0, u16* bs) {
#pragma unroll
    for (int i = 0; i < 2; ++i) {
      const int chunk = wave * 2 + i;
      const int row = chunk * 16 + lrow;
      gload16(Bt + (size_t)(n0 + row) * E_ + k0 + lcol_sw, bs + chunk * 16 * BK);
    }
  };

  const int sl = (fc ^ ((fr >> 1) & 3)) * 8;  // swizzled read slot

  auto compute = [&]() {
    bf16x8 af[4], bfr[4];
#pragma unroll
    for (int mi = 0; mi < 4; ++mi)
      af[mi] = *(const bf16x8*)&aA[(wm + mi * 16 + fr) * BK + sl];
#pragma unroll
    for (int ni = 0; ni < 4; ++ni)
      bfr[ni] = *(const bf16x8*)&bA[(wn + ni * 16 + fr) * BK + sl];
    __builtin_amdgcn_s_setprio(1);
#pragma unroll
    for (int mi = 0; mi < 4; ++mi)
#pragma unroll
      for (int ni = 0; ni < 4; ++ni)
        acc[mi][ni] = mfma16(af[mi], bfr[ni], acc[mi][ni]);
    __builtin_amdgcn_s_setprio(0);
    u16* tp;
    tp = aA; aA = aB; aB = aC; aC = tp;
    tp = bA; bA = bB; bB = bC; bC = tp;
  };

  constexpr int NK = E_ / BK;  // 32 (even)
  // Prologue: A(0) via bank0 -> aA; then A(1)->bank1, B(0); A(2)->bank0, B(1).
  loadA0(0);
  asm volatile("s_waitcnt vmcnt(0)" ::: "memory");
  writeA0(aA);
  loadA1(1 * BK);  loadB(0, bA);
  loadA0(2 * BK);  loadB(1 * BK, bB);
  // queue (oldest first): A(1)x4, B(0)x2, A(2)x4, B(1)x2 = 12

  for (int tt = 0; tt < NK; tt += 2) {
    {  // even sub-iter t = tt: bank1 holds A(t+1); write-late post-barrier
      const int t = tt;
      if (t + 3 < NK) {
        asm volatile("s_waitcnt vmcnt(6)" ::: "memory");  // A(t+1) regs + B(t) LDS
      } else {
        asm volatile("s_waitcnt vmcnt(0)" ::: "memory");
      }
      asm volatile("s_waitcnt lgkmcnt(0)" ::: "memory");  // drain prev A-writes
      __builtin_amdgcn_s_barrier();
      __builtin_amdgcn_sched_barrier(0);
      writeA1(aB);                       // A(t+1) -> buffer that becomes aA
      if (t + 3 < NK) loadA1((t + 3) * BK);
      if (t + 2 < NK) loadB((t + 2) * BK, bC);
      __builtin_amdgcn_sched_barrier(0);
      compute();
    }
    {  // odd sub-iter t = tt+1: bank0 holds A(t+1)
      const int t = tt + 1;
      if (t + 1 < NK) {
        if (t + 3 < NK) {
          asm volatile("s_waitcnt vmcnt(6)" ::: "memory");
        } else {
          asm volatile("s_waitcnt vmcnt(0)" ::: "memory");
        }
      } else {
        asm volatile("s_waitcnt vmcnt(0)" ::: "memory");
      }
      asm volatile("s_waitcnt lgkmcnt(0)" ::: "memory");
      __builtin_amdgcn_s_barrier();
      __builtin_amdgcn_sched_barrier(0);
      if (t + 1 < NK) writeA0(aB);
      if (t + 3 < NK) loadA0((t + 3) * BK);
      if (t + 2 < NK) loadB((t + 2) * BK, bC);
      __builtin_amdgcn_sched_barrier(0);
      compute();
    }
  }

#pragma unroll
  for (int mi = 0; mi < 4; ++mi)
#pragma unroll
    for (int ni = 0; ni < 4; ++ni)
#pragma unroll
      for (int r = 0; r < 4; ++r) {
        const int m = m0 + wm + mi * 16 + (fc << 2) + r;
        const int n = n0 + wn + ni * 16 + fr;
        const float v = acc[mi][ni][r];
        const int b = m >> 11, s = m & (S_ - 1), h = n >> 6, d = n & 63;
        if (z != 2) {
          outp[((((size_t)b * H_ + h) * S_ + s) << 6) + d] = f2bf(v);
        } else {
          outp[(((size_t)b * H_ + h) * D_ + d) * S_ + s] = f2bf(v);
        }
      }
}

// ---------------- output projection GEMM (pipelined + swizzled, BM=64) -----
__global__ __launch_bounds__(256, 4) void oproj_gemm(
    const u16* __restrict__ A, const u16* __restrict__ Bt,
    const float* __restrict__ bias, float* __restrict__ outp) {
  constexpr int BM = 64, BN = 128, BK = 32;
  __shared__ alignas(16) u16 As[3][BM * BK];
  __shared__ alignas(16) u16 Bs[3][BN * BK];

  const int wg = blockIdx.x;           // 0..511, xcd-bucketed
  const int xcd = wg & 7, idx = wg >> 3;
  const int nb = idx & 7, mi_ = idx >> 3;
  const int m0 = (xcd * 8 + mi_) * BM, n0 = nb * BN;

  const int tid = threadIdx.x;
  const int wave = tid >> 6, lane = tid & 63;
  const int wm = (wave >> 1) * 32, wn = (wave & 1) * 64;
  const int fr = lane & 15, fc = lane >> 4;
  const int lrow = lane >> 2;
  const int lcol_sw = (((lane & 3) ^ ((lrow >> 1) & 3)) * 8);

  f32x4 acc[2][4] = {};

  u16 *aA = As[0], *aB = As[1], *aC = As[2];
  u16 *bA = Bs[0], *bB = Bs[1], *bC = Bs[2];

  auto stage = [&](int k0, u16* as, u16* bs) {
#pragma unroll
    for (int i = 0; i < 3; ++i) {
      const int c = wave + 4 * i;
      if (c < 4)
        gload16(A + (size_t)(m0 + c * 16 + lrow) * E_ + k0 + lcol_sw, as + c * 16 * BK);
      else
        gload16(Bt + (size_t)(n0 + (c - 4) * 16 + lrow) * E_ + k0 + lcol_sw,
                bs + (c - 4) * 16 * BK);
    }
  };

  constexpr int NK = E_ / BK;  // 32
  stage(0, aA, bA);
  stage(BK, aB, bB);

  const int sl = (fc ^ ((fr >> 1) & 3)) * 8;

  for (int t = 0; t < NK; ++t) {
    if (t + 1 < NK) {
      asm volatile("s_waitcnt vmcnt(3)" ::: "memory");
    } else {
      asm volatile("s_waitcnt vmcnt(0)" ::: "memory");
    }
    __builtin_amdgcn_s_barrier();
    __builtin_amdgcn_sched_barrier(0);

    if (t + 2 < NK) stage((t + 2) * BK, aC, bC);

    bf16x8 af[2], bfr[4];
#pragma unroll
    for (int mi = 0; mi < 2; ++mi)
      af[mi] = *(const bf16x8*)&aA[(wm + mi * 16 + fr) * BK + sl];
#pragma unroll
    for (int ni = 0; ni < 4; ++ni)
      bfr[ni] = *(const bf16x8*)&bA[(wn + ni * 16 + fr) * BK + sl];
    __builtin_amdgcn_s_setprio(1);
#pragma unroll
    for (int mi = 0; mi < 2; ++mi)
#pragma unroll
      for (int ni = 0; ni < 4; ++ni)
        acc[mi][ni] = mfma16(af[mi], bfr[ni], acc[mi][ni]);
    __builtin_amdgcn_s_setprio(0);

    u16* tp;
    tp = aA; aA = aB; aB = aC; aC = tp;
    tp = bA; bA = bB; bB = bC; bC = tp;
  }

#pragma unroll
  for (int mi = 0; mi < 2; ++mi)
#pragma unroll
    for (int ni = 0; ni < 4; ++ni)
#pragma unroll
      for (int r = 0; r < 4; ++r) {
        const int m = m0 + wm + mi * 16 + (fc << 2) + r;
        const int n = n0 + wn + ni * 16 + fr;
        outp[(size_t)m * E_ + n] = acc[mi][ni][r] + bias[n];
      }
}

// ---------------- causal flash attention (KV-tile 128, 2-deep ping-pong) ----
__device__ __forceinline__ void stage_kv128(
    const u16* __restrict__ Kh_head, const u16* __restrict__ Vt_head,
    int kv0, u16* kb, u16* vb, int wq, int lane) {
#pragma unroll
  for (int hh = 0; hh < 2; ++hh)
    gload16(Kh_head + (size_t)(kv0 + hh * 64 + lane) * D_ + wq * 8,
            kb + wq * 1024 + hh * 512);
#pragma unroll
  for (int i = 0; i < 2; ++i) {
    const int c = 2 * wq + i;
    gload16(Vt_head + (size_t)lane * S_ + kv0 + c * 8, vb + c * 512);
  }
}

__global__ __launch_bounds__(512, 4) void flash_attn(
    const u16* __restrict__ Qh, const u16* __restrict__ Kh,
    const u16* __restrict__ Vt, u16* __restrict__ O) {
  __shared__ alignas(16) u16 Kb[2][8192];   // [buf][chunk*1024 + row*8]
  __shared__ alignas(16) u16 Vb[2][8192];   // [buf][chunk*512 + d*8]

  const int i = blockIdx.x;            // 0..511, snake pairing
  const int ch = i >> 8, p = i & 255;
  const int j = (ch << 8) + ((ch & 1) ? (255 - p) : p);
  const int qt = 15 - (j >> 5);
  const int bh = j & 31;

  const int tid = threadIdx.x;
  const int wq = tid >> 6, lane = tid & 63;

  const int q0 = qt * 128;
  const int b = bh >> 4, h = bh & 15;
  constexpr float SC = 0.125f * 1.4426950408889634f;
  const int fr = lane & 15, fc = lane >> 4;

  const u16* Qbase = Qh + ((size_t)bh * S_ + q0 + wq * 16 + fr) * D_ + 8 * fc;
  const bf16x8 qf0 = *(const bf16x8*)Qbase;
  const bf16x8 qf1 = *(const bf16x8*)(Qbase + 32);
  const u16* Kh_head = Kh + (size_t)bh * S_ * D_;
  const u16* Vt_head = Vt + (size_t)bh * D_ * S_;

  float lacc = 0.f;
  f32x4 oacc[4] = {};
  const int nt = qt + 1;   // 128-row kv tiles

  u16 *kA = Kb[0], *kB = Kb[1];
  u16 *vA = Vb[0], *vB = Vb[1];

  stage_kv128(Kh_head, Vt_head, 0, kA, vA, wq, lane);

  for (int t = 0; t < nt; ++t) {
    asm volatile("s_waitcnt vmcnt(0)" ::: "memory");
    __builtin_amdgcn_s_barrier();
    __builtin_amdgcn_sched_barrier(0);

    if (t + 1 < nt)
      stage_kv128(Kh_head, Vt_head, (t + 1) * 128, kB, vB, wq, lane);

    const u16* kb = kA;
    const u16* vb = vA;
    const bool diag = (t == nt - 1);
    const int qg = q0 + wq * 16 + fr;

#pragma unroll
    for (int hh = 0; hh < 2; ++hh) {
      const int kvb = t * 128 + hh * 64;

      f32x4 sacc[4] = {};
      __builtin_amdgcn_s_setprio(1);
#pragma unroll
      for (int ni = 0; ni < 4; ++ni) {
        const bf16x8 k0 = *(const bf16x8*)&kb[fc * 1024 + hh * 512 + (16 * ni + fr) * 8];
        const bf16x8 k1 = *(const bf16x8*)&kb[(fc + 4) * 1024 + hh * 512 + (16 * ni + fr) * 8];
        sacc[ni] = mfma16(k0, qf0, sacc[ni]);
        sacc[ni] = mfma16(k1, qf1, sacc[ni]);
      }
      __builtin_amdgcn_s_setprio(0);

#pragma unroll
      for (int ni = 0; ni < 4; ++ni)
#pragma unroll
        for (int r = 0; r < 4; ++r) {
          const int kvg = kvb + 16 * ni + 4 * fc + r;
          float pv;
          if (diag && kvg > qg) {
            pv = 0.f;
          } else {
            pv = __builtin_amdgcn_exp2f(sacc[ni][r] * SC);
          }
          sacc[ni][r] = pv;
          lacc += pv;
        }

      unsigned w[4][2];
#pragma unroll
      for (int ni = 0; ni < 4; ++ni) {
        asm("v_cvt_pk_bf16_f32 %0, %1, %2"
            : "=v"(w[ni][0]) : "v"(sacc[ni][0]), "v"(sacc[ni][1]));
        asm("v_cvt_pk_bf16_f32 %0, %1, %2"
            : "=v"(w[ni][1]) : "v"(sacc[ni][2]), "v"(sacc[ni][3]));
      }

      unsigned paw0[4], paw1[4];
#pragma unroll
      for (int pair = 0; pair < 2; ++pair) {
        unsigned xx[2], yy[2], tt2[2];
#pragma unroll
        for (int hh2 = 0; hh2 < 2; ++hh2) {
          unsigned a = w[2 * pair][hh2], bb = w[2 * pair + 1][hh2];
          asm volatile("v_permlane32_swap_b32 %0, %1" : "+v"(a), "+v"(bb));
          xx[hh2] = a; yy[hh2] = bb;
          const unsigned s = (fc & 1) ? a : bb;
          tt2[hh2] = (unsigned)__shfl_xor((int)s, 16);
        }
        unsigned* pw_ = pair ? paw1 : paw0;
        pw_[0] = (fc & 1) ? tt2[0] : xx[0];
        pw_[1] = (fc & 1) ? tt2[1] : xx[1];
        pw_[2] = (fc & 1) ? yy[0] : tt2[0];
        pw_[3] = (fc & 1) ? yy[1] : tt2[1];
      }
      bf16x8 pa0, pa1;
      {
        u32x4 t0 = {paw0[0], paw0[1], paw0[2], paw0[3]};
        u32x4 t1 = {paw1[0], paw1[1], paw1[2], paw1[3]};
        __builtin_memcpy(&pa0, &t0, 16);
        __builtin_memcpy(&pa1, &t1, 16);
      }

      __builtin_amdgcn_s_setprio(1);
#pragma unroll
      for (int nd = 0; nd < 4; ++nd) {
        const bf16x8 v0 = *(const bf16x8*)&vb[(hh * 8 + fc) * 512 + (16 * nd + fr) * 8];
        const bf16x8 v1 = *(const bf16x8*)&vb[(hh * 8 + fc + 4) * 512 + (16 * nd + fr) * 8];
        oacc[nd] = mfma16(pa0, v0, oacc[nd]);
        oacc[nd] = mfma16(pa1, v1, oacc[nd]);
      }
      __builtin_amdgcn_s_setprio(0);
    }

    u16* tk = kA; kA = kB; kB = tk;
    u16* tv = vA; vA = vB; vB = tv;
  }

  float l = lacc;
  l += __shfl_xor(l, 16);
  l += __shfl_xor(l, 32);
  float linv[4];
#pragma unroll
  for (int r = 0; r < 4; ++r)
    linv[r] = __builtin_amdgcn_rcpf(__shfl(l, 4 * fc + r));

#pragma unroll
  for (int nd = 0; nd < 4; ++nd) {
#pragma unroll
    for (int r = 0; r < 4; ++r) {
      const int qr = q0 + wq * 16 + (fc << 2) + r;
      const int d = 16 * nd + fr;
      const float v = oacc[nd][r] * linv[r];
      O[((size_t)b * S_ + qr) * E_ + h * D_ + d] = f2bf(v);
    }
  }
}

// ---------------------------------------------------------------------------
extern "C" void kernel_launch(void* const* d_in, const int* in_sizes, int n_in,
                              void* d_out, int out_size, void* d_ws, size_t ws_size,
                              hipStream_t stream) {
  const float* q  = (const float*)d_in[0];
  const float* k  = (const float*)d_in[1];
  const float* v  = (const float*)d_in[2];
  const float* Wq = (const float*)d_in[3];
  const float* Wk = (const float*)d_in[4];
  const float* Wv = (const float*)d_in[5];
  const float* Wo = (const float*)d_in[6];
  const float* bo = (const float*)d_in[7];

  const size_t nBSE = (size_t)M_ * E_;  // 4M elems
  const size_t nEE  = (size_t)E_ * E_;  // 1M elems
  u16* Wqb = (u16*)d_ws;
  u16* Wkb = Wqb + nEE;
  u16* Wvb = Wkb + nEE;
  u16* Wob = Wvb + nEE;
  u16* Qh  = Wob + nEE;
  u16* Kh  = Qh + nBSE;
  u16* Vt  = Kh + nBSE;
  u16* Oa  = Vt + nBSE;

  CvtArgs ca;
  ca.src[0] = Wq; ca.dst[0] = Wqb; ca.n[0] = (int)nEE;
  ca.src[1] = Wk; ca.dst[1] = Wkb; ca.n[1] = (int)nEE;
  ca.src[2] = Wv; ca.dst[2] = Wvb; ca.n[2] = (int)nEE;
  ca.src[3] = Wo; ca.dst[3] = Wob; ca.n[3] = (int)nEE;
  cvt_kernel<<<dim3(256, 4), 256, 0, stream>>>(ca);

  // Fused Q/K/V projections reading fp32 inputs directly: 768 blocks
  qkv_gemm<<<dim3(768), 256, 0, stream>>>(
      q, k, v, Wqb, Wkb, Wvb, Qh, Kh, Vt);
  // 512 blocks x 512 threads: one 128-row q-tile each, snake pairing
  flash_attn<<<dim3(512), 512, 0, stream>>>(Qh, Kh, Vt, Oa);
  // O-projection: 512 blocks, xcd-bucketed, pipelined
  oproj_gemm<<<dim3(512), 256, 0, stream>>>(Oa, Wob, bo, (float*)d_out);
}